// Round 17
// baseline (1088.904 us; speedup 1.0000x reference)
//
#include <hip/hip_runtime.h>
#include <hip/hip_bf16.h>
#include <stdint.h>
#include <math.h>

typedef __attribute__((ext_vector_type(8))) short bf16x8;
typedef __attribute__((ext_vector_type(4))) float f32x4;
typedef __attribute__((ext_vector_type(4))) unsigned short u16x4;

#define DEV static __device__ __forceinline__

DEV unsigned short f2bf(float f){
  union { float f; unsigned u; } v; v.f = f;
  unsigned r = v.u + 0x7fffu + ((v.u >> 16) & 1u);
  return (unsigned short)(r >> 16);
}

DEV void gload_lds16(const void* g, void* l){
  __builtin_amdgcn_global_load_lds(
      (const __attribute__((address_space(1))) unsigned int*)g,
      (__attribute__((address_space(3))) unsigned int*)l, 16, 0, 0);
}

// ---------------- misc prep ----------------

__global__ __launch_bounds__(256) void k_misc(const unsigned char* __restrict__ mb,
                                              unsigned* __restrict__ flag,
                                              unsigned short* __restrict__ zp){
  __shared__ unsigned s;
  if(threadIdx.x==0) s = 0;
  __syncthreads();
  unsigned any = 0;
  for(int off = threadIdx.x; off < 4096; off += 256) if(off & 3) any |= mb[off];
  if(any) atomicOr(&s, 1u);
  __syncthreads();
  if(threadIdx.x==0) *flag = (s ? 1u : 0u);   // 1 = byte mask, 0 = int32 mask
  for(int i = threadIdx.x; i < 2048; i += 256) zp[i] = 0;
}

__global__ __launch_bounds__(256) void k_cast4(const float* __restrict__ x,
                                               unsigned short* __restrict__ o, int n4){
  for(int i = blockIdx.x*256 + threadIdx.x; i < n4; i += gridDim.x*256){
    f32x4 v = ((const f32x4*)x)[i];
    u16x4 r;
    #pragma unroll
    for(int j=0;j<4;++j) r[j] = f2bf(v[j]);
    ((u16x4*)o)[i] = r;
  }
}

__global__ __launch_bounds__(256) void k_prep_qkv(const float* __restrict__ Wq, const float* __restrict__ Wk,
                                                  const float* __restrict__ Wv, const float* __restrict__ bq,
                                                  const float* __restrict__ bk, const float* __restrict__ bv,
                                                  unsigned short* __restrict__ Wt, float* __restrict__ bias){
  const int total = 1152*384;
  for(int idx = blockIdx.x*blockDim.x + threadIdx.x; idx < total; idx += gridDim.x*blockDim.x){
    int n = idx/384, d = idx%384;
    int mat = n/384, rem = n%384, h = rem/192, e = rem%192;
    const float* W = (mat==0) ? Wq : ((mat==1) ? Wk : Wv);
    Wt[idx] = f2bf(W[((size_t)h*384 + d)*192 + e]);           // Wt[n][d] = W[h][d][e]
    if(d==0){
      const float* bb = (mat==0) ? bq : ((mat==1) ? bk : bv);
      bias[n] = bb[h*192 + e];
    }
  }
}

// tiled transpose: src [R][C] f32 row-major -> dst [C][R] bf16
__global__ __launch_bounds__(256) void k_tr(const float* __restrict__ src,
                                            unsigned short* __restrict__ dst, int R, int C){
  __shared__ float t[32][33];
  const int tx = threadIdx.x & 31, ty = threadIdx.x >> 5;   // ty: 8 rows per pass
  const int c0 = blockIdx.x*32, r0 = blockIdx.y*32;
  #pragma unroll
  for(int i=0;i<32;i+=8) t[ty+i][tx] = src[(size_t)(r0+ty+i)*C + c0+tx];
  __syncthreads();
  #pragma unroll
  for(int i=0;i<32;i+=8) dst[(size_t)(c0+ty+i)*R + r0+tx] = f2bf(t[tx][ty+i]);
}

// ---------------- conv weight prep: MFMA-fragment order ----------------
// src W: [9*CIN][NOUT] f32 (lax WIO flattened). Output frag f = ((nq*9+t)*DTOT+d)*8+fn*2+kk2,
// 1 KB each: lane L, elem j -> B[n = nq*64+fn*16+(L&15)][k = t*CIN + d*64 + kk2*32 + (L>>4)*8 + j].

template<int CIN, int NOUT>
__global__ __launch_bounds__(256)
void k_prepB(const float* __restrict__ W, unsigned short* __restrict__ Bf){
  constexpr int DTOT = CIN/64;
  const int gid = blockIdx.x*256 + threadIdx.x;
  const int lane = gid & 63;
  const int frag = gid >> 6;
  int f = frag;
  const int kk2 = f & 1, fn = (f>>1) & 3; f >>= 3;
  const int d = f % DTOT; f /= DTOT;
  const int t = f % 9;
  const int nq = f / 9;
  const int lane16 = lane & 15, laneh = lane >> 4;
  const int n = nq*64 + fn*16 + lane16;
  const int kbase = t*CIN + d*64 + kk2*32 + laneh*8;
  bf16x8 out;
  #pragma unroll
  for(int j=0;j<8;++j)
    out[j] = (short)f2bf(W[(size_t)(kbase + j)*NOUT + n]);
  *(bf16x8*)(Bf + (size_t)frag*512 + lane*8) = out;
}

// ---------------- plain GEMM (m97-style) for QKV / Wo ----------------
// EPI: 0=QKV(write Q,K,Vt bf16)  1=f32 out stride 384 (+bias)

template<int EPI>
__global__ __launch_bounds__(256)
void k_gemm(const unsigned short* __restrict__ A,
            const unsigned short* __restrict__ Bt,
            const float* __restrict__ bias,
            unsigned short* __restrict__ out_q,
            unsigned short* __restrict__ out_k,
            unsigned short* __restrict__ out_v,
            float* __restrict__ out_f,
            int Ktot, int lda)
{
  constexpr int BK = 64;
  __shared__ __attribute__((aligned(16))) unsigned short As[128*64];
  __shared__ __attribute__((aligned(16))) unsigned short Bs[128*64];
  const int tid = threadIdx.x;
  const int wave = tid >> 6, lane = tid & 63;
  const int lane16 = lane & 15, laneh = lane >> 4;
  const int wm = wave >> 1, wn = wave & 1;

  const int nwg  = gridDim.x*gridDim.y;
  const int flat = blockIdx.y*gridDim.x + blockIdx.x;
  const int swz  = (flat & 7)*(nwg >> 3) + (flat >> 3);
  const int m0 = (swz % gridDim.y) * 128;
  const int n0 = (swz / gridDim.y) * 128;

  f32x4 acc[4][4];
  #pragma unroll
  for(int i=0;i<4;++i)
    #pragma unroll
    for(int j=0;j<4;++j) acc[i][j] = (f32x4){0.f,0.f,0.f,0.f};

  const int nsteps = Ktot / BK;
  for(int ks=0; ks<nsteps; ++ks){
    const int kg = ks*BK;
    __syncthreads();
    #pragma unroll
    for(int q=0;q<4;++q){
      int e0 = (q*256 + tid)*8;
      int row = e0 >> 6, col = e0 & 63;
      gload_lds16(A + (size_t)(m0+row)*lda + kg + col, (char*)As + q*4096 + wave*1024);
    }
    #pragma unroll
    for(int q=0;q<4;++q){
      int e0 = (q*256 + tid)*8;
      int row = e0 >> 6, col = e0 & 63;
      gload_lds16(Bt + (size_t)(n0+row)*Ktot + kg + col, (char*)Bs + q*4096 + wave*1024);
    }
    __syncthreads();
    #pragma unroll
    for(int kk=0; kk<BK; kk+=32){
      bf16x8 af[4], bfr[4];
      #pragma unroll
      for(int fm=0;fm<4;++fm)
        af[fm] = *(const bf16x8*)&As[(wm*64 + fm*16 + lane16)*64 + kk + laneh*8];
      #pragma unroll
      for(int fn=0;fn<4;++fn)
        bfr[fn] = *(const bf16x8*)&Bs[(wn*64 + fn*16 + lane16)*64 + kk + laneh*8];
      #pragma unroll
      for(int fm=0;fm<4;++fm)
        #pragma unroll
        for(int fn=0;fn<4;++fn)
          acc[fm][fn] = __builtin_amdgcn_mfma_f32_16x16x32_bf16(af[fm], bfr[fn], acc[fm][fn], 0, 0, 0);
    }
  }
  #pragma unroll
  for(int fm=0;fm<4;++fm){
    #pragma unroll
    for(int fn=0;fn<4;++fn){
      #pragma unroll
      for(int r=0;r<4;++r){
        int gr = m0 + wm*64 + fm*16 + laneh*4 + r;     // C/D: row=(lane>>4)*4+reg
        int gc = n0 + wn*64 + fn*16 + lane16;          // C/D: col=lane&15
        float c = acc[fm][fn][r] + bias[gc];
        if(EPI==0){
          int mat = gc/384, rem = gc%384, h = rem/192, e = rem%192;
          int b = gr >> 10, s = gr & 1023;
          int bh = b*2 + h;
          if(mat==0)      out_q[((size_t)bh*1024 + s)*192 + e] = f2bf(c);
          else if(mat==1) out_k[((size_t)bh*1024 + s)*192 + e] = f2bf(c);
          else            out_v[((size_t)bh*192 + e)*1024 + s] = f2bf(c);   // V transposed
        } else {
          out_f[(size_t)gr*384 + gc] = c;
        }
      }
    }
  }
}

// ---------------- conv GEMM: barrier-free, LDS-free; A and B frag-direct from global ----
// A-fragment layout is directly loadable: lane L of wave (wm,wn) needs
//   A[m0-4+wm*64+(L&15)+fm*16+t][dblk*64 + kk2*32 + (L>>4)*8 + j]  (16B/lane).
// Taps flow in ONE flattened loop (ntap = dper*9, always even) with seamless b0/b1
// B-prefetch across d-block boundaries; no __syncthreads anywhere -> no pipeline breaks,
// zero cross-wave interaction (race-free by construction). T5 setprio kept on MFMA.
// OOB halo rows: per-lane select to zero page (same pattern as R1-R15).
// EPI: 2 = relu + bf16 out (stride NOUT)   3 = f32 partial slab by blockIdx.z (split over d)

DEV void ldB8(bf16x8 (&r)[8], const unsigned short* __restrict__ Bf,
              int nq, int t, int DTOT, int dblk, int lane){
  const unsigned short* fb = Bf + ((size_t)((nq*9 + t)*DTOT) + dblk)*4096 + lane*8;
  #pragma unroll
  for(int f=0; f<8; ++f) r[f] = *(const bf16x8*)(fb + f*512);   // f = fn*2+kk2
}

template<int EPI, int CIN, int NOUT>
__global__ __launch_bounds__(256)
void k_conv(const unsigned short* __restrict__ A,   // [16384][CIN]
            const unsigned short* __restrict__ Bf,  // frag-ordered weights
            const float* __restrict__ bias,
            unsigned short* __restrict__ out_h,
            float* __restrict__ out_f,
            float* __restrict__ out_f2,             // slab 2 (z==2) for conv2 z=3
            const unsigned short* __restrict__ zp)
{
  const int tid = threadIdx.x;
  const int wave = tid >> 6, lane = tid & 63;
  const int lane16 = lane & 15, laneh = lane >> 4;
  const int wm = wave >> 1, wn = wave & 1;

  const int nwg  = gridDim.x*gridDim.y;
  const int flat = blockIdx.y*gridDim.x + blockIdx.x;
  const int swz  = (flat & 7)*(nwg >> 3) + (flat >> 3);
  const int m0 = (swz % gridDim.y) * 128;
  const int n0 = (swz / gridDim.y) * 128;

  constexpr int DTOT = CIN/64;
  const int dper = DTOT / gridDim.z;
  const int dlo  = blockIdx.z * dper;
  const int srow = m0 & 1023;   // tile start within its batch (128 | 1024)
  const int nq   = (n0 >> 6) + wn;

  // per-lane A base: batch-local row s0 (fm=0, t=0), col octet laneh*8
  const int s0 = srow - 4 + wm*64 + lane16;
  const unsigned short* Ab = A + ((size_t)(m0 - 4 + wm*64 + lane16))*CIN + laneh*8;

  f32x4 acc[4][4];
  #pragma unroll
  for(int i=0;i<4;++i)
    #pragma unroll
    for(int j=0;j<4;++j) acc[i][j] = (f32x4){0.f,0.f,0.f,0.f};

  bf16x8 b0[8], b1[8];
  ldB8(b0, Bf, nq, 0, DTOT, dlo, lane);      // prologue: tap 0 of first d-block

  const int ntap = dper*9;                   // 54 (conv1) / 72 (conv2): always even
  int tA = 0, dA = dlo;                      // tap/dblk consumed this iteration
  int tP = 1, dP = dlo;                      // next tap/dblk to prefetch

  // one compute body: A-frags direct from global (zp for OOB rows), B from cur
  #define CONV_TAP(CUR)                                                        \
    __builtin_amdgcn_s_setprio(1);                                             \
    _Pragma("unroll")                                                          \
    for(int kk2=0; kk2<2; ++kk2){                                              \
      _Pragma("unroll")                                                        \
      for(int fm=0; fm<4; ++fm){                                               \
        int s = s0 + fm*16 + tA;                                               \
        const unsigned short* ap = (s >= 0 && s < 1024)                        \
            ? Ab + (size_t)(fm*16 + tA)*CIN + dA*64 + kk2*32 : zp;             \
        bf16x8 af = *(const bf16x8*)ap;                                        \
        _Pragma("unroll")                                                      \
        for(int fn=0; fn<4; ++fn)                                              \
          acc[fm][fn] = __builtin_amdgcn_mfma_f32_16x16x32_bf16(af, CUR[fn*2+kk2], acc[fm][fn], 0, 0, 0); \
      }                                                                        \
    }                                                                          \
    __builtin_amdgcn_s_setprio(0);                                             \
    if(++tA == 9){ tA = 0; ++dA; }

  for(int i=0; i<ntap; i+=2){
    // tap i: consume b0, prefetch into b1
    if(i+1 < ntap){ ldB8(b1, Bf, nq, tP, DTOT, dP, lane); if(++tP==9){tP=0;++dP;} }
    CONV_TAP(b0)
    // tap i+1: consume b1, prefetch into b0
    if(i+2 < ntap){ ldB8(b0, Bf, nq, tP, DTOT, dP, lane); if(++tP==9){tP=0;++dP;} }
    CONV_TAP(b1)
  }
  #undef CONV_TAP

  // ---- epilogue ----
  float* out_p = (EPI==3 && blockIdx.z==2) ? out_f2
               : out_f + (size_t)blockIdx.z * 16384 * 384;
  #pragma unroll
  for(int fm=0;fm<4;++fm){
    #pragma unroll
    for(int fn=0;fn<4;++fn){
      #pragma unroll
      for(int r=0;r<4;++r){
        int gr = m0 + wm*64 + fm*16 + laneh*4 + r;
        int gc = n0 + wn*64 + fn*16 + lane16;
        float c = acc[fm][fn][r];
        if(EPI==2){
          c += bias[gc];
          out_h[(size_t)gr*NOUT + gc] = f2bf(fmaxf(c, 0.f));
        } else {
          out_p[(size_t)gr*384 + gc] = c;
        }
      }
    }
  }
}

// bias-only add (conv2 fallback): out[i] = p[i] + bias[i % 384]
__global__ __launch_bounds__(256)
void k_bias(const float* __restrict__ p, const float* __restrict__ bias,
            float* __restrict__ out, int n4){
  for(int i = blockIdx.x*256 + threadIdx.x; i < n4; i += gridDim.x*256){
    f32x4 a = ((const f32x4*)p)[i];
    f32x4 bi = ((const f32x4*)bias)[i % 96];
    ((f32x4*)out)[i] = a + bi;
  }
}

// ---------------- attention: flash, cooperative LDS-staged K/V (R7, proven) ----------------

__global__ __launch_bounds__(256)
void k_attn(const unsigned short* __restrict__ Q,
            const unsigned short* __restrict__ Kb,
            const unsigned short* __restrict__ Vt,
            const void* __restrict__ mask,
            const unsigned* __restrict__ flag,
            unsigned short* __restrict__ O)
{
  __shared__ __attribute__((aligned(16))) unsigned short Ks[64*192];   // 24 KB
  __shared__ __attribute__((aligned(16))) unsigned short Vs[192*64];   // 24 KB
  __shared__ __attribute__((aligned(16))) unsigned short P_lds[4*16*64]; // 8 KB

  const int flat = blockIdx.y*gridDim.x + blockIdx.x;   // grid (16,32)
  const int w = (flat & 7)*64 + (flat >> 3);
  const int bh = w >> 4, qb = w & 15;
  const int b = bh >> 1, h = bh & 1;
  const int tid = threadIdx.x;
  const int wave = tid >> 6, lane = tid & 63;
  const int lane16 = lane & 15, laneh = lane >> 4;
  const int q0 = qb*64 + wave*16;
  const bool mbyte = (*flag != 0);
  const unsigned char* m8 = (const unsigned char*)mask;
  const int* m32 = (const int*)mask;
  unsigned short* Pw = P_lds + wave*1024;

  bf16x8 qa[6];
  {
    const unsigned short* Qrow = Q + ((size_t)bh*1024 + q0 + lane16)*192 + laneh*8;
    #pragma unroll
    for(int kk=0; kk<6; ++kk) qa[kk] = *(const bf16x8*)(Qrow + kk*32);
  }

  f32x4 accO[12];
  #pragma unroll
  for(int i=0;i<12;++i) accO[i] = (f32x4){0.f,0.f,0.f,0.f};
  float mrow[4], lrow[4];
  #pragma unroll
  for(int r=0;r<4;++r){ mrow[r] = -1e30f; lrow[r] = 0.f; }

  const float rs = 0.05103103630798288f;  // 1/sqrt(384)
  const size_t mbase = (size_t)b * 1024 * 1024;
  const unsigned short* Kbh = Kb + (size_t)bh*1024*192;
  const unsigned short* Vbh = Vt + (size_t)bh*192*1024;

  for(int t0=0; t0<1024; t0+=64){
    unsigned mskv[4][4];
    #pragma unroll
    for(int tf=0; tf<4; ++tf){
      #pragma unroll
      for(int r=0;r<4;++r){
        size_t mi = mbase + (size_t)(q0 + laneh*4 + r)*1024 + t0 + tf*16 + lane16;
        mskv[tf][r] = mbyte ? (unsigned)m8[mi] : (unsigned)m32[mi];
      }
    }
    __syncthreads();
    #pragma unroll
    for(int q=0;q<6;++q){
      int P = (q*256 + tid)*16;
      int row = P/384, cb = P%384;
      gload_lds16(Kbh + (size_t)(t0 + row)*192 + ((cb ^ ((row&7)<<4)) >> 1),
                  (char*)Ks + q*4096 + wave*1024);
    }
    #pragma unroll
    for(int q=0;q<6;++q){
      int P = (q*256 + tid)*16;
      int row = P >> 7, cb = P & 127;
      gload_lds16(Vbh + (size_t)row*1024 + t0 + ((cb ^ ((row&7)<<4)) >> 1),
                  (char*)Vs + q*4096 + wave*1024);
    }
    __syncthreads();
    f32x4 sc[4];
    #pragma unroll
    for(int i=0;i<4;++i) sc[i] = (f32x4){0.f,0.f,0.f,0.f};
    #pragma unroll
    for(int kk=0; kk<6; ++kk){
      #pragma unroll
      for(int tf=0; tf<4; ++tf){
        int tt = tf*16 + lane16;
        const bf16x8* kp = (const bf16x8*)((const char*)Ks +
            tt*384 + ((kk*64 + laneh*16) ^ ((tt&7)<<4)));
        sc[tf] = __builtin_amdgcn_mfma_f32_16x16x32_bf16(qa[kk], *kp, sc[tf], 0, 0, 0);
      }
    }
    #pragma unroll
    for(int tf=0; tf<4; ++tf)
      #pragma unroll
      for(int r=0;r<4;++r)
        sc[tf][r] = mskv[tf][r] ? -1e9f : sc[tf][r]*rs;
    float tm[4];
    #pragma unroll
    for(int r=0;r<4;++r){
      float v = fmaxf(fmaxf(sc[0][r],sc[1][r]), fmaxf(sc[2][r],sc[3][r]));
      v = fmaxf(v, __shfl_xor(v,1)); v = fmaxf(v, __shfl_xor(v,2));
      v = fmaxf(v, __shfl_xor(v,4)); v = fmaxf(v, __shfl_xor(v,8));
      tm[r] = v;
    }
    float scale_o[4];
    #pragma unroll
    for(int r=0;r<4;++r){
      float mn = fmaxf(mrow[r], tm[r]);
      scale_o[r] = __expf(mrow[r] - mn);
      mrow[r] = mn;
    }
    float ts[4] = {0.f,0.f,0.f,0.f};
    #pragma unroll
    for(int tf=0; tf<4; ++tf){
      #pragma unroll
      for(int r=0;r<4;++r){
        float p = __expf(sc[tf][r] - mrow[r]);
        ts[r] += p;
        Pw[(laneh*4 + r)*64 + tf*16 + lane16] = f2bf(p);
      }
    }
    #pragma unroll
    for(int r=0;r<4;++r){
      float v = ts[r];
      v += __shfl_xor(v,1); v += __shfl_xor(v,2); v += __shfl_xor(v,4); v += __shfl_xor(v,8);
      lrow[r] = lrow[r]*scale_o[r] + v;
    }
    #pragma unroll
    for(int ef=0; ef<12; ++ef)
      #pragma unroll
      for(int r=0;r<4;++r) accO[ef][r] *= scale_o[r];
    #pragma unroll
    for(int kk=0; kk<64; kk+=32){
      bf16x8 pa = *(const bf16x8*)&Pw[lane16*64 + kk + laneh*8];
      #pragma unroll
      for(int ef=0; ef<12; ++ef){
        int er = ef*16 + lane16;
        const bf16x8* vp = (const bf16x8*)((const char*)Vs +
            er*128 + (((kk + laneh*8)*2) ^ ((er&7)<<4)));
        accO[ef] = __builtin_amdgcn_mfma_f32_16x16x32_bf16(pa, *vp, accO[ef], 0, 0, 0);
      }
    }
  }
  #pragma unroll
  for(int ef=0; ef<12; ++ef){
    #pragma unroll
    for(int r=0;r<4;++r){
      int qr = q0 + laneh*4 + r;
      int e  = ef*16 + lane16;
      float o = accO[ef][r] / lrow[r];
      O[((size_t)b*1024 + qr)*384 + h*192 + e] = f2bf(o);
    }
  }
}

// ---------------- LayerNorm (1 wave per row of 384) ----------------

__global__ __launch_bounds__(256)
void k_ln(const float* __restrict__ a, const float* __restrict__ resid,
          const float* __restrict__ g, const float* __restrict__ beta,
          float* __restrict__ outf, unsigned short* __restrict__ outbf)
{
  const int row = blockIdx.x*4 + (threadIdx.x >> 6);
  const int lane = threadIdx.x & 63;
  const float* pa = a + (size_t)row*384;
  const float* pr = resid + (size_t)row*384;
  float v[6], s = 0.f, s2 = 0.f;
  #pragma unroll
  for(int j=0;j<6;++j){
    int e = lane + j*64;
    float t = pa[e] + pr[e];
    v[j] = t; s += t; s2 += t*t;
  }
  #pragma unroll
  for(int o=1;o<64;o<<=1){ s += __shfl_xor(s,o); s2 += __shfl_xor(s2,o); }
  float mean = s * (1.f/384.f);
  float var  = s2 * (1.f/384.f) - mean*mean;
  float inv  = rsqrtf(var + 1e-5f);
  #pragma unroll
  for(int j=0;j<6;++j){
    int e = lane + j*64;
    float t = (v[j]-mean)*inv*g[e] + beta[e];
    if(outf)  outf[(size_t)row*384 + e] = t;
    if(outbf) outbf[(size_t)row*384 + e] = f2bf(t);
  }
}

// fused: LN( p0+p1+p2+bias  + resid ) -> outf   (conv2 3-slab reduce + LN2)
__global__ __launch_bounds__(256)
void k_lnred3(const float* __restrict__ p0, const float* __restrict__ p2,
              const float* __restrict__ bias, const float* __restrict__ resid,
              const float* __restrict__ g, const float* __restrict__ beta,
              float* __restrict__ outf)
{
  const int row = blockIdx.x*4 + (threadIdx.x >> 6);
  const int lane = threadIdx.x & 63;
  const float* p1 = p0 + (size_t)16384*384;
  const size_t base = (size_t)row*384;
  float v[6], s = 0.f, s2 = 0.f;
  #pragma unroll
  for(int j=0;j<6;++j){
    int e = lane + j*64;
    float t = p0[base+e] + p1[base+e] + p2[base+e] + bias[e] + resid[base+e];
    v[j] = t; s += t; s2 += t*t;
  }
  #pragma unroll
  for(int o=1;o<64;o<<=1){ s += __shfl_xor(s,o); s2 += __shfl_xor(s2,o); }
  float mean = s * (1.f/384.f);
  float var  = s2 * (1.f/384.f) - mean*mean;
  float inv  = rsqrtf(var + 1e-5f);
  #pragma unroll
  for(int j=0;j<6;++j){
    int e = lane + j*64;
    outf[base + e] = (v[j]-mean)*inv*g[e] + beta[e];
  }
}

// ---------------- host ----------------

extern "C" void kernel_launch(void* const* d_in, const int* in_sizes, int n_in,
                              void* d_out, int out_size, void* d_ws, size_t ws_size,
                              hipStream_t stream)
{
  const float* x   = (const float*)d_in[0];
  const void*  mask= d_in[1];
  const float* Wq  = (const float*)d_in[2];
  const float* bq  = (const float*)d_in[3];
  const float* Wk  = (const float*)d_in[4];
  const float* bk  = (const float*)d_in[5];
  const float* Wv  = (const float*)d_in[6];
  const float* bv  = (const float*)d_in[7];
  const float* Wo  = (const float*)d_in[8];
  const float* bo  = (const float*)d_in[9];
  const float* Wc1 = (const float*)d_in[10];
  const float* bc1 = (const float*)d_in[11];
  const float* Wc2 = (const float*)d_in[12];
  const float* bc2 = (const float*)d_in[13];
  const float* g1  = (const float*)d_in[14];
  const float* be1 = (const float*)d_in[15];
  const float* g2  = (const float*)d_in[16];
  const float* be2 = (const float*)d_in[17];

  // R13-R15 (proven) layout; wc1t/wc2t hold frag-ordered weights (same 10.6 MB).
  char* ws = (char*)d_ws;
  size_t off = 0;
  auto alloc = [&](size_t bytes)->char*{
    char* p = ws + off; off += (bytes + 255) & ~(size_t)255; return p;
  };
  unsigned short* zp   = (unsigned short*)alloc(4096);
  unsigned*       flag = (unsigned*)alloc(256);
  unsigned short* wqkv = (unsigned short*)alloc((size_t)1152*384*2);
  float*          bqkv = (float*)alloc((size_t)1152*4);
  unsigned short* wot  = (unsigned short*)alloc((size_t)384*384*2);
  unsigned short* wc1t = (unsigned short*)alloc((size_t)1536*3456*2);   // 10368 KB frag buf
  unsigned short* wc2t = (unsigned short*)alloc((size_t)384*13824*2);   // 10368 KB frag buf
  unsigned short* xbf  = (unsigned short*)alloc((size_t)16384*384*2);   // 12582912 B
  unsigned short* Qb   = (unsigned short*)alloc((size_t)32*1024*192*2); // 12582912 B (contiguous w/ xbf)
  unsigned short* Kbuf = (unsigned short*)alloc((size_t)32*1024*192*2);
  unsigned short* Vt   = (unsigned short*)alloc((size_t)32*192*1024*2);
  float*          yb   = (float*)alloc((size_t)16384*384*4);
  unsigned short* hb   = (unsigned short*)alloc((size_t)16384*1536*2);
  // overlays (lifetimes strictly ordered on the stream):
  unsigned short* Obf  = xbf;          // attention out (xbf dead after QKV gemm; consumed by Wo gemm)
  unsigned short* x1bf = Qb;           // LN1 bf16 out (Qb dead after attn; consumed by conv1)
  float*          x1f  = (float*)Kbuf; // LN1 f32 out, spans Kbuf+Vt (dead after attn)
  float*          zb   = yb;           // conv2 out, fallback only (yb dead after LN1)
  // conv2 z=3 split: slabs 0,1 in dedicated pb tail (guarded); slab 2 overlays xbf+Qb
  // (exactly 25165824 B contiguous; both dead once conv1 has consumed x1bf). Proven R8-R15.
  const size_t pb_bytes = (size_t)2*16384*384*4;
  const bool   splitk   = (ws_size >= off + pb_bytes);
  float*       pb       = (float*)alloc(pb_bytes);
  float*       slab2    = (float*)xbf;

  k_misc<<<1,256,0,stream>>>((const unsigned char*)mask, flag, zp);
  k_cast4<<<2048,256,0,stream>>>(x, xbf, 16384*384/4);
  k_prep_qkv<<<1728,256,0,stream>>>(Wq,Wk,Wv,bq,bk,bv,wqkv,bqkv);
  k_tr<<<dim3(12,12),256,0,stream>>>(Wo, wot, 384, 384);
  k_prepB<384,1536><<<2592,256,0,stream>>>(Wc1, wc1t);   // 10368 frags x 64 lanes
  k_prepB<1536,384><<<2592,256,0,stream>>>(Wc2, wc2t);

  // QKV projection: [16384,384] x [384,1152]
  k_gemm<0><<<dim3(9,128),256,0,stream>>>(xbf, wqkv, bqkv, Qb, Kbuf, Vt,
                                          nullptr, 384, 384);
  // attention (cooperative LDS-staged K/V)
  k_attn<<<dim3(16,32),256,0,stream>>>(Qb, Kbuf, Vt, mask, flag, Obf);
  // O @ Wo + bo
  k_gemm<1><<<dim3(3,128),256,0,stream>>>(Obf, wot, bo, nullptr,nullptr,nullptr,
                                          yb, 384, 384);
  // LN1 (adds residual x)
  k_ln<<<4096,256,0,stream>>>(yb, x, g1, be1, x1f, x1bf);
  // conv1: barrier-free frag-direct A+B, relu  (grid 12x128 = 1536 blocks)
  k_conv<2,384,1536><<<dim3(12,128,1),256,0,stream>>>(x1bf, wc1t, bc1, hb, nullptr, nullptr, zp);
  if(splitk){
    // conv2: z=3 over d (dper=8) -> slabs 0,1 in pb, slab 2 in xbf+Qb overlay
    k_conv<3,1536,384><<<dim3(3,128,3),256,0,stream>>>(hb, wc2t, nullptr, nullptr, pb, slab2, zp);
    // fused 3-slab reduce + bias + residual + LN2 -> d_out
    k_lnred3<<<4096,256,0,stream>>>(pb, slab2, bc2, x1f, g2, be2, (float*)d_out);
  } else {
    // fallback: single-z f32 partial into zb, bias add, then LN2
    k_conv<3,1536,384><<<dim3(3,128,1),256,0,stream>>>(hb, wc2t, nullptr, nullptr, zb, nullptr, zp);
    k_bias<<<2048,256,0,stream>>>(zb, bc2, zb, 16384*384/4);
    k_ln<<<4096,256,0,stream>>>(zb, x1f, g2, be2, (float*)d_out, nullptr);
  }
}

// Round 18
// 1086.904 us; speedup vs baseline: 1.0018x; 1.0018x over previous
//
#include <hip/hip_runtime.h>
#include <hip/hip_bf16.h>
#include <stdint.h>
#include <math.h>

typedef __attribute__((ext_vector_type(8))) short bf16x8;
typedef __attribute__((ext_vector_type(4))) float f32x4;
typedef __attribute__((ext_vector_type(4))) unsigned short u16x4;

#define DEV static __device__ __forceinline__

DEV unsigned short f2bf(float f){
  union { float f; unsigned u; } v; v.f = f;
  unsigned r = v.u + 0x7fffu + ((v.u >> 16) & 1u);
  return (unsigned short)(r >> 16);
}

DEV void gload_lds16(const void* g, void* l){
  __builtin_amdgcn_global_load_lds(
      (const __attribute__((address_space(1))) unsigned int*)g,
      (__attribute__((address_space(3))) unsigned int*)l, 16, 0, 0);
}

// ---------------- misc prep ----------------

__global__ __launch_bounds__(256) void k_misc(const unsigned char* __restrict__ mb,
                                              unsigned* __restrict__ flag,
                                              unsigned short* __restrict__ zp){
  __shared__ unsigned s;
  if(threadIdx.x==0) s = 0;
  __syncthreads();
  unsigned any = 0;
  for(int off = threadIdx.x; off < 4096; off += 256) if(off & 3) any |= mb[off];
  if(any) atomicOr(&s, 1u);
  __syncthreads();
  if(threadIdx.x==0) *flag = (s ? 1u : 0u);   // 1 = byte mask, 0 = int32 mask
  for(int i = threadIdx.x; i < 2048; i += 256) zp[i] = 0;
}

__global__ __launch_bounds__(256) void k_cast4(const float* __restrict__ x,
                                               unsigned short* __restrict__ o, int n4){
  for(int i = blockIdx.x*256 + threadIdx.x; i < n4; i += gridDim.x*256){
    f32x4 v = ((const f32x4*)x)[i];
    u16x4 r;
    #pragma unroll
    for(int j=0;j<4;++j) r[j] = f2bf(v[j]);
    ((u16x4*)o)[i] = r;
  }
}

__global__ __launch_bounds__(256) void k_prep_qkv(const float* __restrict__ Wq, const float* __restrict__ Wk,
                                                  const float* __restrict__ Wv, const float* __restrict__ bq,
                                                  const float* __restrict__ bk, const float* __restrict__ bv,
                                                  unsigned short* __restrict__ Wt, float* __restrict__ bias){
  const int total = 1152*384;
  for(int idx = blockIdx.x*blockDim.x + threadIdx.x; idx < total; idx += gridDim.x*blockDim.x){
    int n = idx/384, d = idx%384;
    int mat = n/384, rem = n%384, h = rem/192, e = rem%192;
    const float* W = (mat==0) ? Wq : ((mat==1) ? Wk : Wv);
    Wt[idx] = f2bf(W[((size_t)h*384 + d)*192 + e]);           // Wt[n][d] = W[h][d][e]
    if(d==0){
      const float* bb = (mat==0) ? bq : ((mat==1) ? bk : bv);
      bias[n] = bb[h*192 + e];
    }
  }
}

// tiled transpose: src [R][C] f32 row-major -> dst [C][R] bf16
__global__ __launch_bounds__(256) void k_tr(const float* __restrict__ src,
                                            unsigned short* __restrict__ dst, int R, int C){
  __shared__ float t[32][33];
  const int tx = threadIdx.x & 31, ty = threadIdx.x >> 5;   // ty: 8 rows per pass
  const int c0 = blockIdx.x*32, r0 = blockIdx.y*32;
  #pragma unroll
  for(int i=0;i<32;i+=8) t[ty+i][tx] = src[(size_t)(r0+ty+i)*C + c0+tx];
  __syncthreads();
  #pragma unroll
  for(int i=0;i<32;i+=8) dst[(size_t)(c0+ty+i)*R + r0+tx] = f2bf(t[tx][ty+i]);
}

// ---------------- conv weight prep: MFMA-fragment order ----------------
// src W: [9*CIN][NOUT] f32 (lax WIO flattened). Output frag f = ((nq*9+t)*DTOT+d)*8+fn*2+kk2,
// 1 KB each: lane L, elem j -> B[n = nq*64+fn*16+(L&15)][k = t*CIN + d*64 + kk2*32 + (L>>4)*8 + j].

template<int CIN, int NOUT>
__global__ __launch_bounds__(256)
void k_prepB(const float* __restrict__ W, unsigned short* __restrict__ Bf){
  constexpr int DTOT = CIN/64;
  const int gid = blockIdx.x*256 + threadIdx.x;
  const int lane = gid & 63;
  const int frag = gid >> 6;
  int f = frag;
  const int kk2 = f & 1, fn = (f>>1) & 3; f >>= 3;
  const int d = f % DTOT; f /= DTOT;
  const int t = f % 9;
  const int nq = f / 9;
  const int lane16 = lane & 15, laneh = lane >> 4;
  const int n = nq*64 + fn*16 + lane16;
  const int kbase = t*CIN + d*64 + kk2*32 + laneh*8;
  bf16x8 out;
  #pragma unroll
  for(int j=0;j<8;++j)
    out[j] = (short)f2bf(W[(size_t)(kbase + j)*NOUT + n]);
  *(bf16x8*)(Bf + (size_t)frag*512 + lane*8) = out;
}

// ---------------- plain GEMM (m97-style) for QKV / Wo ----------------
// EPI: 0=QKV(write Q,K,Vt bf16)  1=f32 out stride 384 (+bias)

template<int EPI>
__global__ __launch_bounds__(256)
void k_gemm(const unsigned short* __restrict__ A,
            const unsigned short* __restrict__ Bt,
            const float* __restrict__ bias,
            unsigned short* __restrict__ out_q,
            unsigned short* __restrict__ out_k,
            unsigned short* __restrict__ out_v,
            float* __restrict__ out_f,
            int Ktot, int lda)
{
  constexpr int BK = 64;
  __shared__ __attribute__((aligned(16))) unsigned short As[128*64];
  __shared__ __attribute__((aligned(16))) unsigned short Bs[128*64];
  const int tid = threadIdx.x;
  const int wave = tid >> 6, lane = tid & 63;
  const int lane16 = lane & 15, laneh = lane >> 4;
  const int wm = wave >> 1, wn = wave & 1;

  const int nwg  = gridDim.x*gridDim.y;
  const int flat = blockIdx.y*gridDim.x + blockIdx.x;
  const int swz  = (flat & 7)*(nwg >> 3) + (flat >> 3);
  const int m0 = (swz % gridDim.y) * 128;
  const int n0 = (swz / gridDim.y) * 128;

  f32x4 acc[4][4];
  #pragma unroll
  for(int i=0;i<4;++i)
    #pragma unroll
    for(int j=0;j<4;++j) acc[i][j] = (f32x4){0.f,0.f,0.f,0.f};

  const int nsteps = Ktot / BK;
  for(int ks=0; ks<nsteps; ++ks){
    const int kg = ks*BK;
    __syncthreads();
    #pragma unroll
    for(int q=0;q<4;++q){
      int e0 = (q*256 + tid)*8;
      int row = e0 >> 6, col = e0 & 63;
      gload_lds16(A + (size_t)(m0+row)*lda + kg + col, (char*)As + q*4096 + wave*1024);
    }
    #pragma unroll
    for(int q=0;q<4;++q){
      int e0 = (q*256 + tid)*8;
      int row = e0 >> 6, col = e0 & 63;
      gload_lds16(Bt + (size_t)(n0+row)*Ktot + kg + col, (char*)Bs + q*4096 + wave*1024);
    }
    __syncthreads();
    #pragma unroll
    for(int kk=0; kk<BK; kk+=32){
      bf16x8 af[4], bfr[4];
      #pragma unroll
      for(int fm=0;fm<4;++fm)
        af[fm] = *(const bf16x8*)&As[(wm*64 + fm*16 + lane16)*64 + kk + laneh*8];
      #pragma unroll
      for(int fn=0;fn<4;++fn)
        bfr[fn] = *(const bf16x8*)&Bs[(wn*64 + fn*16 + lane16)*64 + kk + laneh*8];
      #pragma unroll
      for(int fm=0;fm<4;++fm)
        #pragma unroll
        for(int fn=0;fn<4;++fn)
          acc[fm][fn] = __builtin_amdgcn_mfma_f32_16x16x32_bf16(af[fm], bfr[fn], acc[fm][fn], 0, 0, 0);
    }
  }
  #pragma unroll
  for(int fm=0;fm<4;++fm){
    #pragma unroll
    for(int fn=0;fn<4;++fn){
      #pragma unroll
      for(int r=0;r<4;++r){
        int gr = m0 + wm*64 + fm*16 + laneh*4 + r;     // C/D: row=(lane>>4)*4+reg
        int gc = n0 + wn*64 + fn*16 + lane16;          // C/D: col=lane&15
        float c = acc[fm][fn][r] + bias[gc];
        if(EPI==0){
          int mat = gc/384, rem = gc%384, h = rem/192, e = rem%192;
          int b = gr >> 10, s = gr & 1023;
          int bh = b*2 + h;
          if(mat==0)      out_q[((size_t)bh*1024 + s)*192 + e] = f2bf(c);
          else if(mat==1) out_k[((size_t)bh*1024 + s)*192 + e] = f2bf(c);
          else            out_v[((size_t)bh*192 + e)*1024 + s] = f2bf(c);   // V transposed
        } else {
          out_f[(size_t)gr*384 + gc] = c;
        }
      }
    }
  }
}

// ---------------- conv GEMM: barrier-free, LDS-free; A and B frag-direct from global ----
// A-fragment layout is directly loadable: lane L of wave (wm,wn) needs
//   A[m0-4+wm*64+(L&15)+fm*16+t][dblk*64 + kk2*32 + (L>>4)*8 + j]  (16B/lane).
// Taps flow in ONE flattened loop (ntap = dper*9, always even) with seamless b0/b1
// B-prefetch across d-block boundaries; no __syncthreads anywhere -> no pipeline breaks,
// zero cross-wave interaction (race-free by construction). T5 setprio kept on MFMA.
// OOB halo rows: per-lane select to zero page (same pattern as R1-R15).
// EPI: 2 = relu + bf16 out (stride NOUT)   3 = f32 partial slab by blockIdx.z (split over d)

DEV void ldB8(bf16x8 (&r)[8], const unsigned short* __restrict__ Bf,
              int nq, int t, int DTOT, int dblk, int lane){
  const unsigned short* fb = Bf + ((size_t)((nq*9 + t)*DTOT) + dblk)*4096 + lane*8;
  #pragma unroll
  for(int f=0; f<8; ++f) r[f] = *(const bf16x8*)(fb + f*512);   // f = fn*2+kk2
}

template<int EPI, int CIN, int NOUT>
__global__ __launch_bounds__(256)
void k_conv(const unsigned short* __restrict__ A,   // [16384][CIN]
            const unsigned short* __restrict__ Bf,  // frag-ordered weights
            const float* __restrict__ bias,
            unsigned short* __restrict__ out_h,
            float* __restrict__ out_f,
            float* __restrict__ out_f2,             // slab 2 (z==2) for conv2 z=3
            const unsigned short* __restrict__ zp)
{
  const int tid = threadIdx.x;
  const int wave = tid >> 6, lane = tid & 63;
  const int lane16 = lane & 15, laneh = lane >> 4;
  const int wm = wave >> 1, wn = wave & 1;

  const int nwg  = gridDim.x*gridDim.y;
  const int flat = blockIdx.y*gridDim.x + blockIdx.x;
  const int swz  = (flat & 7)*(nwg >> 3) + (flat >> 3);
  const int m0 = (swz % gridDim.y) * 128;
  const int n0 = (swz / gridDim.y) * 128;

  constexpr int DTOT = CIN/64;
  const int dper = DTOT / gridDim.z;
  const int dlo  = blockIdx.z * dper;
  const int srow = m0 & 1023;   // tile start within its batch (128 | 1024)
  const int nq   = (n0 >> 6) + wn;

  // per-lane A base: batch-local row s0 (fm=0, t=0), col octet laneh*8
  const int s0 = srow - 4 + wm*64 + lane16;
  const unsigned short* Ab = A + ((size_t)(m0 - 4 + wm*64 + lane16))*CIN + laneh*8;

  f32x4 acc[4][4];
  #pragma unroll
  for(int i=0;i<4;++i)
    #pragma unroll
    for(int j=0;j<4;++j) acc[i][j] = (f32x4){0.f,0.f,0.f,0.f};

  bf16x8 b0[8], b1[8];
  ldB8(b0, Bf, nq, 0, DTOT, dlo, lane);      // prologue: tap 0 of first d-block

  const int ntap = dper*9;                   // 54 (conv1) / 72 (conv2): always even
  int tA = 0, dA = dlo;                      // tap/dblk consumed this iteration
  int tP = 1, dP = dlo;                      // next tap/dblk to prefetch

  // one compute body: A-frags direct from global (zp for OOB rows), B from cur
  #define CONV_TAP(CUR)                                                        \
    __builtin_amdgcn_s_setprio(1);                                             \
    _Pragma("unroll")                                                          \
    for(int kk2=0; kk2<2; ++kk2){                                              \
      _Pragma("unroll")                                                        \
      for(int fm=0; fm<4; ++fm){                                               \
        int s = s0 + fm*16 + tA;                                               \
        const unsigned short* ap = (s >= 0 && s < 1024)                        \
            ? Ab + (size_t)(fm*16 + tA)*CIN + dA*64 + kk2*32 : zp;             \
        bf16x8 af = *(const bf16x8*)ap;                                        \
        _Pragma("unroll")                                                      \
        for(int fn=0; fn<4; ++fn)                                              \
          acc[fm][fn] = __builtin_amdgcn_mfma_f32_16x16x32_bf16(af, CUR[fn*2+kk2], acc[fm][fn], 0, 0, 0); \
      }                                                                        \
    }                                                                          \
    __builtin_amdgcn_s_setprio(0);                                             \
    if(++tA == 9){ tA = 0; ++dA; }

  for(int i=0; i<ntap; i+=2){
    // tap i: consume b0, prefetch into b1
    if(i+1 < ntap){ ldB8(b1, Bf, nq, tP, DTOT, dP, lane); if(++tP==9){tP=0;++dP;} }
    CONV_TAP(b0)
    // tap i+1: consume b1, prefetch into b0
    if(i+2 < ntap){ ldB8(b0, Bf, nq, tP, DTOT, dP, lane); if(++tP==9){tP=0;++dP;} }
    CONV_TAP(b1)
  }
  #undef CONV_TAP

  // ---- epilogue ----
  float* out_p = (EPI==3 && blockIdx.z==2) ? out_f2
               : out_f + (size_t)blockIdx.z * 16384 * 384;
  #pragma unroll
  for(int fm=0;fm<4;++fm){
    #pragma unroll
    for(int fn=0;fn<4;++fn){
      #pragma unroll
      for(int r=0;r<4;++r){
        int gr = m0 + wm*64 + fm*16 + laneh*4 + r;
        int gc = n0 + wn*64 + fn*16 + lane16;
        float c = acc[fm][fn][r];
        if(EPI==2){
          c += bias[gc];
          out_h[(size_t)gr*NOUT + gc] = f2bf(fmaxf(c, 0.f));
        } else {
          out_p[(size_t)gr*384 + gc] = c;
        }
      }
    }
  }
}

// bias-only add (conv2 fallback): out[i] = p[i] + bias[i % 384]
__global__ __launch_bounds__(256)
void k_bias(const float* __restrict__ p, const float* __restrict__ bias,
            float* __restrict__ out, int n4){
  for(int i = blockIdx.x*256 + threadIdx.x; i < n4; i += gridDim.x*256){
    f32x4 a = ((const f32x4*)p)[i];
    f32x4 bi = ((const f32x4*)bias)[i % 96];
    ((f32x4*)out)[i] = a + bi;
  }
}

// ---------------- attention: flash, cooperative LDS-staged K/V (R7, proven) ----------------

__global__ __launch_bounds__(256)
void k_attn(const unsigned short* __restrict__ Q,
            const unsigned short* __restrict__ Kb,
            const unsigned short* __restrict__ Vt,
            const void* __restrict__ mask,
            const unsigned* __restrict__ flag,
            unsigned short* __restrict__ O)
{
  __shared__ __attribute__((aligned(16))) unsigned short Ks[64*192];   // 24 KB
  __shared__ __attribute__((aligned(16))) unsigned short Vs[192*64];   // 24 KB
  __shared__ __attribute__((aligned(16))) unsigned short P_lds[4*16*64]; // 8 KB

  const int flat = blockIdx.y*gridDim.x + blockIdx.x;   // grid (16,32)
  const int w = (flat & 7)*64 + (flat >> 3);
  const int bh = w >> 4, qb = w & 15;
  const int b = bh >> 1, h = bh & 1;
  const int tid = threadIdx.x;
  const int wave = tid >> 6, lane = tid & 63;
  const int lane16 = lane & 15, laneh = lane >> 4;
  const int q0 = qb*64 + wave*16;
  const bool mbyte = (*flag != 0);
  const unsigned char* m8 = (const unsigned char*)mask;
  const int* m32 = (const int*)mask;
  unsigned short* Pw = P_lds + wave*1024;

  bf16x8 qa[6];
  {
    const unsigned short* Qrow = Q + ((size_t)bh*1024 + q0 + lane16)*192 + laneh*8;
    #pragma unroll
    for(int kk=0; kk<6; ++kk) qa[kk] = *(const bf16x8*)(Qrow + kk*32);
  }

  f32x4 accO[12];
  #pragma unroll
  for(int i=0;i<12;++i) accO[i] = (f32x4){0.f,0.f,0.f,0.f};
  float mrow[4], lrow[4];
  #pragma unroll
  for(int r=0;r<4;++r){ mrow[r] = -1e30f; lrow[r] = 0.f; }

  const float rs = 0.05103103630798288f;  // 1/sqrt(384)
  const size_t mbase = (size_t)b * 1024 * 1024;
  const unsigned short* Kbh = Kb + (size_t)bh*1024*192;
  const unsigned short* Vbh = Vt + (size_t)bh*192*1024;

  for(int t0=0; t0<1024; t0+=64){
    unsigned mskv[4][4];
    #pragma unroll
    for(int tf=0; tf<4; ++tf){
      #pragma unroll
      for(int r=0;r<4;++r){
        size_t mi = mbase + (size_t)(q0 + laneh*4 + r)*1024 + t0 + tf*16 + lane16;
        mskv[tf][r] = mbyte ? (unsigned)m8[mi] : (unsigned)m32[mi];
      }
    }
    __syncthreads();
    #pragma unroll
    for(int q=0;q<6;++q){
      int P = (q*256 + tid)*16;
      int row = P/384, cb = P%384;
      gload_lds16(Kbh + (size_t)(t0 + row)*192 + ((cb ^ ((row&7)<<4)) >> 1),
                  (char*)Ks + q*4096 + wave*1024);
    }
    #pragma unroll
    for(int q=0;q<6;++q){
      int P = (q*256 + tid)*16;
      int row = P >> 7, cb = P & 127;
      gload_lds16(Vbh + (size_t)row*1024 + t0 + ((cb ^ ((row&7)<<4)) >> 1),
                  (char*)Vs + q*4096 + wave*1024);
    }
    __syncthreads();
    f32x4 sc[4];
    #pragma unroll
    for(int i=0;i<4;++i) sc[i] = (f32x4){0.f,0.f,0.f,0.f};
    #pragma unroll
    for(int kk=0; kk<6; ++kk){
      #pragma unroll
      for(int tf=0; tf<4; ++tf){
        int tt = tf*16 + lane16;
        const bf16x8* kp = (const bf16x8*)((const char*)Ks +
            tt*384 + ((kk*64 + laneh*16) ^ ((tt&7)<<4)));
        sc[tf] = __builtin_amdgcn_mfma_f32_16x16x32_bf16(qa[kk], *kp, sc[tf], 0, 0, 0);
      }
    }
    #pragma unroll
    for(int tf=0; tf<4; ++tf)
      #pragma unroll
      for(int r=0;r<4;++r)
        sc[tf][r] = mskv[tf][r] ? -1e9f : sc[tf][r]*rs;
    float tm[4];
    #pragma unroll
    for(int r=0;r<4;++r){
      float v = fmaxf(fmaxf(sc[0][r],sc[1][r]), fmaxf(sc[2][r],sc[3][r]));
      v = fmaxf(v, __shfl_xor(v,1)); v = fmaxf(v, __shfl_xor(v,2));
      v = fmaxf(v, __shfl_xor(v,4)); v = fmaxf(v, __shfl_xor(v,8));
      tm[r] = v;
    }
    float scale_o[4];
    #pragma unroll
    for(int r=0;r<4;++r){
      float mn = fmaxf(mrow[r], tm[r]);
      scale_o[r] = __expf(mrow[r] - mn);
      mrow[r] = mn;
    }
    float ts[4] = {0.f,0.f,0.f,0.f};
    #pragma unroll
    for(int tf=0; tf<4; ++tf){
      #pragma unroll
      for(int r=0;r<4;++r){
        float p = __expf(sc[tf][r] - mrow[r]);
        ts[r] += p;
        Pw[(laneh*4 + r)*64 + tf*16 + lane16] = f2bf(p);
      }
    }
    #pragma unroll
    for(int r=0;r<4;++r){
      float v = ts[r];
      v += __shfl_xor(v,1); v += __shfl_xor(v,2); v += __shfl_xor(v,4); v += __shfl_xor(v,8);
      lrow[r] = lrow[r]*scale_o[r] + v;
    }
    #pragma unroll
    for(int ef=0; ef<12; ++ef)
      #pragma unroll
      for(int r=0;r<4;++r) accO[ef][r] *= scale_o[r];
    #pragma unroll
    for(int kk=0; kk<64; kk+=32){
      bf16x8 pa = *(const bf16x8*)&Pw[lane16*64 + kk + laneh*8];
      #pragma unroll
      for(int ef=0; ef<12; ++ef){
        int er = ef*16 + lane16;
        const bf16x8* vp = (const bf16x8*)((const char*)Vs +
            er*128 + (((kk + laneh*8)*2) ^ ((er&7)<<4)));
        accO[ef] = __builtin_amdgcn_mfma_f32_16x16x32_bf16(pa, *vp, accO[ef], 0, 0, 0);
      }
    }
  }
  #pragma unroll
  for(int ef=0; ef<12; ++ef){
    #pragma unroll
    for(int r=0;r<4;++r){
      int qr = q0 + laneh*4 + r;
      int e  = ef*16 + lane16;
      float o = accO[ef][r] / lrow[r];
      O[((size_t)b*1024 + qr)*384 + h*192 + e] = f2bf(o);
    }
  }
}

// ---------------- LayerNorm (1 wave per row of 384) ----------------

__global__ __launch_bounds__(256)
void k_ln(const float* __restrict__ a, const float* __restrict__ resid,
          const float* __restrict__ g, const float* __restrict__ beta,
          float* __restrict__ outf, unsigned short* __restrict__ outbf)
{
  const int row = blockIdx.x*4 + (threadIdx.x >> 6);
  const int lane = threadIdx.x & 63;
  const float* pa = a + (size_t)row*384;
  const float* pr = resid + (size_t)row*384;
  float v[6], s = 0.f, s2 = 0.f;
  #pragma unroll
  for(int j=0;j<6;++j){
    int e = lane + j*64;
    float t = pa[e] + pr[e];
    v[j] = t; s += t; s2 += t*t;
  }
  #pragma unroll
  for(int o=1;o<64;o<<=1){ s += __shfl_xor(s,o); s2 += __shfl_xor(s2,o); }
  float mean = s * (1.f/384.f);
  float var  = s2 * (1.f/384.f) - mean*mean;
  float inv  = rsqrtf(var + 1e-5f);
  #pragma unroll
  for(int j=0;j<6;++j){
    int e = lane + j*64;
    float t = (v[j]-mean)*inv*g[e] + beta[e];
    if(outf)  outf[(size_t)row*384 + e] = t;
    if(outbf) outbf[(size_t)row*384 + e] = f2bf(t);
  }
}

// fused: LN( p0+p1+p2+bias  + resid ) -> outf   (conv2 3-slab reduce + LN2)
__global__ __launch_bounds__(256)
void k_lnred3(const float* __restrict__ p0, const float* __restrict__ p2,
              const float* __restrict__ bias, const float* __restrict__ resid,
              const float* __restrict__ g, const float* __restrict__ beta,
              float* __restrict__ outf)
{
  const int row = blockIdx.x*4 + (threadIdx.x >> 6);
  const int lane = threadIdx.x & 63;
  const float* p1 = p0 + (size_t)16384*384;
  const size_t base = (size_t)row*384;
  float v[6], s = 0.f, s2 = 0.f;
  #pragma unroll
  for(int j=0;j<6;++j){
    int e = lane + j*64;
    float t = p0[base+e] + p1[base+e] + p2[base+e] + bias[e] + resid[base+e];
    v[j] = t; s += t; s2 += t*t;
  }
  #pragma unroll
  for(int o=1;o<64;o<<=1){ s += __shfl_xor(s,o); s2 += __shfl_xor(s2,o); }
  float mean = s * (1.f/384.f);
  float var  = s2 * (1.f/384.f) - mean*mean;
  float inv  = rsqrtf(var + 1e-5f);
  #pragma unroll
  for(int j=0;j<6;++j){
    int e = lane + j*64;
    outf[base + e] = (v[j]-mean)*inv*g[e] + beta[e];
  }
}

// ---------------- host ----------------

extern "C" void kernel_launch(void* const* d_in, const int* in_sizes, int n_in,
                              void* d_out, int out_size, void* d_ws, size_t ws_size,
                              hipStream_t stream)
{
  const float* x   = (const float*)d_in[0];
  const void*  mask= d_in[1];
  const float* Wq  = (const float*)d_in[2];
  const float* bq  = (const float*)d_in[3];
  const float* Wk  = (const float*)d_in[4];
  const float* bk  = (const float*)d_in[5];
  const float* Wv  = (const float*)d_in[6];
  const float* bv  = (const float*)d_in[7];
  const float* Wo  = (const float*)d_in[8];
  const float* bo  = (const float*)d_in[9];
  const float* Wc1 = (const float*)d_in[10];
  const float* bc1 = (const float*)d_in[11];
  const float* Wc2 = (const float*)d_in[12];
  const float* bc2 = (const float*)d_in[13];
  const float* g1  = (const float*)d_in[14];
  const float* be1 = (const float*)d_in[15];
  const float* g2  = (const float*)d_in[16];
  const float* be2 = (const float*)d_in[17];

  // R13-R15 (proven) layout; wc1t/wc2t hold frag-ordered weights (same 10.6 MB).
  char* ws = (char*)d_ws;
  size_t off = 0;
  auto alloc = [&](size_t bytes)->char*{
    char* p = ws + off; off += (bytes + 255) & ~(size_t)255; return p;
  };
  unsigned short* zp   = (unsigned short*)alloc(4096);
  unsigned*       flag = (unsigned*)alloc(256);
  unsigned short* wqkv = (unsigned short*)alloc((size_t)1152*384*2);
  float*          bqkv = (float*)alloc((size_t)1152*4);
  unsigned short* wot  = (unsigned short*)alloc((size_t)384*384*2);
  unsigned short* wc1t = (unsigned short*)alloc((size_t)1536*3456*2);   // 10368 KB frag buf
  unsigned short* wc2t = (unsigned short*)alloc((size_t)384*13824*2);   // 10368 KB frag buf
  unsigned short* xbf  = (unsigned short*)alloc((size_t)16384*384*2);   // 12582912 B
  unsigned short* Qb   = (unsigned short*)alloc((size_t)32*1024*192*2); // 12582912 B (contiguous w/ xbf)
  unsigned short* Kbuf = (unsigned short*)alloc((size_t)32*1024*192*2);
  unsigned short* Vt   = (unsigned short*)alloc((size_t)32*192*1024*2);
  float*          yb   = (float*)alloc((size_t)16384*384*4);
  unsigned short* hb   = (unsigned short*)alloc((size_t)16384*1536*2);
  // overlays (lifetimes strictly ordered on the stream):
  unsigned short* Obf  = xbf;          // attention out (xbf dead after QKV gemm; consumed by Wo gemm)
  unsigned short* x1bf = Qb;           // LN1 bf16 out (Qb dead after attn; consumed by conv1)
  float*          x1f  = (float*)Kbuf; // LN1 f32 out, spans Kbuf+Vt (dead after attn)
  float*          zb   = yb;           // conv2 out, fallback only (yb dead after LN1)
  // conv2 z=3 split: slabs 0,1 in dedicated pb tail (guarded); slab 2 overlays xbf+Qb
  // (exactly 25165824 B contiguous; both dead once conv1 has consumed x1bf). Proven R8-R15.
  const size_t pb_bytes = (size_t)2*16384*384*4;
  const bool   splitk   = (ws_size >= off + pb_bytes);
  float*       pb       = (float*)alloc(pb_bytes);
  float*       slab2    = (float*)xbf;

  k_misc<<<1,256,0,stream>>>((const unsigned char*)mask, flag, zp);
  k_cast4<<<2048,256,0,stream>>>(x, xbf, 16384*384/4);
  k_prep_qkv<<<1728,256,0,stream>>>(Wq,Wk,Wv,bq,bk,bv,wqkv,bqkv);
  k_tr<<<dim3(12,12),256,0,stream>>>(Wo, wot, 384, 384);
  k_prepB<384,1536><<<2592,256,0,stream>>>(Wc1, wc1t);   // 10368 frags x 64 lanes
  k_prepB<1536,384><<<2592,256,0,stream>>>(Wc2, wc2t);

  // QKV projection: [16384,384] x [384,1152]
  k_gemm<0><<<dim3(9,128),256,0,stream>>>(xbf, wqkv, bqkv, Qb, Kbuf, Vt,
                                          nullptr, 384, 384);
  // attention (cooperative LDS-staged K/V)
  k_attn<<<dim3(16,32),256,0,stream>>>(Qb, Kbuf, Vt, mask, flag, Obf);
  // O @ Wo + bo
  k_gemm<1><<<dim3(3,128),256,0,stream>>>(Obf, wot, bo, nullptr,nullptr,nullptr,
                                          yb, 384, 384);
  // LN1 (adds residual x)
  k_ln<<<4096,256,0,stream>>>(yb, x, g1, be1, x1f, x1bf);
  // conv1: barrier-free frag-direct A+B, relu  (grid 12x128 = 1536 blocks)
  k_conv<2,384,1536><<<dim3(12,128,1),256,0,stream>>>(x1bf, wc1t, bc1, hb, nullptr, nullptr, zp);
  if(splitk){
    // conv2: z=3 over d (dper=8) -> slabs 0,1 in pb, slab 2 in xbf+Qb overlay
    k_conv<3,1536,384><<<dim3(3,128,3),256,0,stream>>>(hb, wc2t, nullptr, nullptr, pb, slab2, zp);
    // fused 3-slab reduce + bias + residual + LN2 -> d_out
    k_lnred3<<<4096,256,0,stream>>>(pb, slab2, bc2, x1f, g2, be2, (float*)d_out);
  } else {
    // fallback: single-z f32 partial into zb, bias add, then LN2
    k_conv<3,1536,384><<<dim3(3,128,1),256,0,stream>>>(hb, wc2t, nullptr, nullptr, zb, nullptr, zp);
    k_bias<<<2048,256,0,stream>>>(zb, bc2, zb, 16384*384/4);
    k_ln<<<4096,256,0,stream>>>(zb, x1f, g2, be2, (float*)d_out, nullptr);
  }
}

// Round 19
// 528.754 us; speedup vs baseline: 2.0594x; 2.0556x over previous
//
#include <hip/hip_runtime.h>
#include <hip/hip_bf16.h>
#include <stdint.h>
#include <math.h>

typedef __attribute__((ext_vector_type(8))) short bf16x8;
typedef __attribute__((ext_vector_type(4))) float f32x4;
typedef __attribute__((ext_vector_type(4))) unsigned short u16x4;

#define DEV static __device__ __forceinline__

DEV unsigned short f2bf(float f){
  union { float f; unsigned u; } v; v.f = f;
  unsigned r = v.u + 0x7fffu + ((v.u >> 16) & 1u);
  return (unsigned short)(r >> 16);
}

DEV void gload_lds16(const void* g, void* l){
  __builtin_amdgcn_global_load_lds(
      (const __attribute__((address_space(1))) unsigned int*)g,
      (__attribute__((address_space(3))) unsigned int*)l, 16, 0, 0);
}

// ---------------- misc prep ----------------

__global__ __launch_bounds__(256) void k_misc(const unsigned char* __restrict__ mb,
                                              unsigned* __restrict__ flag,
                                              unsigned short* __restrict__ zp){
  __shared__ unsigned s;
  if(threadIdx.x==0) s = 0;
  __syncthreads();
  unsigned any = 0;
  for(int off = threadIdx.x; off < 4096; off += 256) if(off & 3) any |= mb[off];
  if(any) atomicOr(&s, 1u);
  __syncthreads();
  if(threadIdx.x==0) *flag = (s ? 1u : 0u);   // 1 = byte mask, 0 = int32 mask
  for(int i = threadIdx.x; i < 2048; i += 256) zp[i] = 0;
}

__global__ __launch_bounds__(256) void k_cast4(const float* __restrict__ x,
                                               unsigned short* __restrict__ o, int n4){
  for(int i = blockIdx.x*256 + threadIdx.x; i < n4; i += gridDim.x*256){
    f32x4 v = ((const f32x4*)x)[i];
    u16x4 r;
    #pragma unroll
    for(int j=0;j<4;++j) r[j] = f2bf(v[j]);
    ((u16x4*)o)[i] = r;
  }
}

__global__ __launch_bounds__(256) void k_prep_qkv(const float* __restrict__ Wq, const float* __restrict__ Wk,
                                                  const float* __restrict__ Wv, const float* __restrict__ bq,
                                                  const float* __restrict__ bk, const float* __restrict__ bv,
                                                  unsigned short* __restrict__ Wt, float* __restrict__ bias){
  const int total = 1152*384;
  for(int idx = blockIdx.x*blockDim.x + threadIdx.x; idx < total; idx += gridDim.x*blockDim.x){
    int n = idx/384, d = idx%384;
    int mat = n/384, rem = n%384, h = rem/192, e = rem%192;
    const float* W = (mat==0) ? Wq : ((mat==1) ? Wk : Wv);
    Wt[idx] = f2bf(W[((size_t)h*384 + d)*192 + e]);           // Wt[n][d] = W[h][d][e]
    if(d==0){
      const float* bb = (mat==0) ? bq : ((mat==1) ? bk : bv);
      bias[n] = bb[h*192 + e];
    }
  }
}

// tiled transpose: src [R][C] f32 row-major -> dst [C][R] bf16
__global__ __launch_bounds__(256) void k_tr(const float* __restrict__ src,
                                            unsigned short* __restrict__ dst, int R, int C){
  __shared__ float t[32][33];
  const int tx = threadIdx.x & 31, ty = threadIdx.x >> 5;   // ty: 8 rows per pass
  const int c0 = blockIdx.x*32, r0 = blockIdx.y*32;
  #pragma unroll
  for(int i=0;i<32;i+=8) t[ty+i][tx] = src[(size_t)(r0+ty+i)*C + c0+tx];
  __syncthreads();
  #pragma unroll
  for(int i=0;i<32;i+=8) dst[(size_t)(c0+ty+i)*R + r0+tx] = f2bf(t[tx][ty+i]);
}

// ---------------- conv weight prep: MFMA-fragment order ----------------
// src W: [9*CIN][NOUT] f32 (lax WIO flattened). Output frag f = ((nq*9+t)*DTOT+d)*8+fn*2+kk2,
// 1 KB each: lane L, elem j -> B[n = nq*64+fn*16+(L&15)][k = t*CIN + d*64 + kk2*32 + (L>>4)*8 + j].

template<int CIN, int NOUT>
__global__ __launch_bounds__(256)
void k_prepB(const float* __restrict__ W, unsigned short* __restrict__ Bf){
  constexpr int DTOT = CIN/64;
  const int gid = blockIdx.x*256 + threadIdx.x;
  const int lane = gid & 63;
  const int frag = gid >> 6;
  int f = frag;
  const int kk2 = f & 1, fn = (f>>1) & 3; f >>= 3;
  const int d = f % DTOT; f /= DTOT;
  const int t = f % 9;
  const int nq = f / 9;
  const int lane16 = lane & 15, laneh = lane >> 4;
  const int n = nq*64 + fn*16 + lane16;
  const int kbase = t*CIN + d*64 + kk2*32 + laneh*8;
  bf16x8 out;
  #pragma unroll
  for(int j=0;j<8;++j)
    out[j] = (short)f2bf(W[(size_t)(kbase + j)*NOUT + n]);
  *(bf16x8*)(Bf + (size_t)frag*512 + lane*8) = out;
}

// ---------------- plain GEMM (m97-style) for QKV / Wo ----------------
// EPI: 0=QKV(write Q,K,Vt bf16)  1=f32 out stride 384 (+bias)

template<int EPI>
__global__ __launch_bounds__(256)
void k_gemm(const unsigned short* __restrict__ A,
            const unsigned short* __restrict__ Bt,
            const float* __restrict__ bias,
            unsigned short* __restrict__ out_q,
            unsigned short* __restrict__ out_k,
            unsigned short* __restrict__ out_v,
            float* __restrict__ out_f,
            int Ktot, int lda)
{
  constexpr int BK = 64;
  __shared__ __attribute__((aligned(16))) unsigned short As[128*64];
  __shared__ __attribute__((aligned(16))) unsigned short Bs[128*64];
  const int tid = threadIdx.x;
  const int wave = tid >> 6, lane = tid & 63;
  const int lane16 = lane & 15, laneh = lane >> 4;
  const int wm = wave >> 1, wn = wave & 1;

  const int nwg  = gridDim.x*gridDim.y;
  const int flat = blockIdx.y*gridDim.x + blockIdx.x;
  const int swz  = (flat & 7)*(nwg >> 3) + (flat >> 3);
  const int m0 = (swz % gridDim.y) * 128;
  const int n0 = (swz / gridDim.y) * 128;

  f32x4 acc[4][4];
  #pragma unroll
  for(int i=0;i<4;++i)
    #pragma unroll
    for(int j=0;j<4;++j) acc[i][j] = (f32x4){0.f,0.f,0.f,0.f};

  const int nsteps = Ktot / BK;
  for(int ks=0; ks<nsteps; ++ks){
    const int kg = ks*BK;
    __syncthreads();
    #pragma unroll
    for(int q=0;q<4;++q){
      int e0 = (q*256 + tid)*8;
      int row = e0 >> 6, col = e0 & 63;
      gload_lds16(A + (size_t)(m0+row)*lda + kg + col, (char*)As + q*4096 + wave*1024);
    }
    #pragma unroll
    for(int q=0;q<4;++q){
      int e0 = (q*256 + tid)*8;
      int row = e0 >> 6, col = e0 & 63;
      gload_lds16(Bt + (size_t)(n0+row)*Ktot + kg + col, (char*)Bs + q*4096 + wave*1024);
    }
    __syncthreads();
    #pragma unroll
    for(int kk=0; kk<BK; kk+=32){
      bf16x8 af[4], bfr[4];
      #pragma unroll
      for(int fm=0;fm<4;++fm)
        af[fm] = *(const bf16x8*)&As[(wm*64 + fm*16 + lane16)*64 + kk + laneh*8];
      #pragma unroll
      for(int fn=0;fn<4;++fn)
        bfr[fn] = *(const bf16x8*)&Bs[(wn*64 + fn*16 + lane16)*64 + kk + laneh*8];
      #pragma unroll
      for(int fm=0;fm<4;++fm)
        #pragma unroll
        for(int fn=0;fn<4;++fn)
          acc[fm][fn] = __builtin_amdgcn_mfma_f32_16x16x32_bf16(af[fm], bfr[fn], acc[fm][fn], 0, 0, 0);
    }
  }
  #pragma unroll
  for(int fm=0;fm<4;++fm){
    #pragma unroll
    for(int fn=0;fn<4;++fn){
      #pragma unroll
      for(int r=0;r<4;++r){
        int gr = m0 + wm*64 + fm*16 + laneh*4 + r;     // C/D: row=(lane>>4)*4+reg
        int gc = n0 + wn*64 + fn*16 + lane16;          // C/D: col=lane&15
        float c = acc[fm][fn][r] + bias[gc];
        if(EPI==0){
          int mat = gc/384, rem = gc%384, h = rem/192, e = rem%192;
          int b = gr >> 10, s = gr & 1023;
          int bh = b*2 + h;
          if(mat==0)      out_q[((size_t)bh*1024 + s)*192 + e] = f2bf(c);
          else if(mat==1) out_k[((size_t)bh*1024 + s)*192 + e] = f2bf(c);
          else            out_v[((size_t)bh*192 + e)*1024 + s] = f2bf(c);   // V transposed
        } else {
          out_f[(size_t)gr*384 + gc] = c;
        }
      }
    }
  }
}

// ---------------- conv GEMM: A-halo in LDS, B frag-direct, T5 setprio on MFMA ----------
// R15-proven optimum (529 us): wave 64Mx64N, acc[4][4]; A-halo staged via gload_lds with
// rule-#21 swizzle involution (conflict-free); frag-ordered B loaded global->VGPR with
// 2-buffer prefetch; setprio(1) around MFMA cluster (T5, +6% in this role-split regime).
// Lesson R16: A must NOT be loaded frag-direct from global (16 scattered lines/load,
// dependent L2 round-trips in the MFMA loop -> 3.3x regression). Activations stay in LDS.
// EPI: 2 = relu + bf16 out (stride NOUT)   3 = f32 partial slab by blockIdx.z (split over d)

DEV void ldB8(bf16x8 (&r)[8], const unsigned short* __restrict__ Bf,
              int nq, int t, int DTOT, int dblk, int lane){
  const unsigned short* fb = Bf + ((size_t)((nq*9 + t)*DTOT) + dblk)*4096 + lane*8;
  #pragma unroll
  for(int f=0; f<8; ++f) r[f] = *(const bf16x8*)(fb + f*512);   // f = fn*2+kk2
}

template<int EPI, int CIN, int NOUT>
__global__ __launch_bounds__(256)
void k_conv(const unsigned short* __restrict__ A,   // [16384][CIN]
            const unsigned short* __restrict__ Bf,  // frag-ordered weights
            const float* __restrict__ bias,
            unsigned short* __restrict__ out_h,
            float* __restrict__ out_f,
            float* __restrict__ out_f2,             // slab 2 (z==2) for conv2 z=3
            const unsigned short* __restrict__ zp)
{
  __shared__ __attribute__((aligned(16))) unsigned short Ah[160*64];   // 20.5 KB
  const int tid = threadIdx.x;
  const int wave = tid >> 6, lane = tid & 63;
  const int lane16 = lane & 15, laneh = lane >> 4;
  const int wm = wave >> 1, wn = wave & 1;

  const int nwg  = gridDim.x*gridDim.y;
  const int flat = blockIdx.y*gridDim.x + blockIdx.x;
  const int swz  = (flat & 7)*(nwg >> 3) + (flat >> 3);
  const int m0 = (swz % gridDim.y) * 128;
  const int n0 = (swz / gridDim.y) * 128;

  constexpr int DTOT = CIN/64;
  const int dper = DTOT / gridDim.z;
  const int dlo  = blockIdx.z * dper;
  const int srow = m0 & 1023;   // tile start within its batch (128 | 1024)
  const int nq   = (n0 >> 6) + wn;

  f32x4 acc[4][4];
  #pragma unroll
  for(int i=0;i<4;++i)
    #pragma unroll
    for(int j=0;j<4;++j) acc[i][j] = (f32x4){0.f,0.f,0.f,0.f};

  bf16x8 b0[8], b1[8];

  for(int db=0; db<dper; ++db){
    const int dblk = dlo + db;
    if(db) __syncthreads();           // all waves done reading Ah for prev d-block
    // ---- stage A-halo (swizzled source, linear dest; rule-#21 involution) ----
    #pragma unroll
    for(int q=0;q<5;++q){
      int P = (q*256 + tid)*16;
      int row = P >> 7, cb = P & 127;
      int cs  = (cb ^ ((row&7)<<4)) >> 1;
      int s = srow - 4 + row;
      const unsigned short* src = (s >= 0 && s < 1024)
          ? A + (size_t)(m0 - 4 + row)*CIN + dblk*64 + cs : zp;
      gload_lds16(src, (char*)Ah + q*4096 + wave*1024);
    }
    // prologue B load for tap 0 (overlaps the gload_lds drain below)
    ldB8(b0, Bf, nq, 0, DTOT, dblk, lane);
    __syncthreads();                  // A staged (compiler drains vmcnt before barrier)
    // ---- 9 taps, no barriers; B for tap t+1 issued before tap t's compute ----
    #pragma unroll
    for(int t=0; t<9; ++t){
      bf16x8 (&cur)[8] = (t & 1) ? b1 : b0;   // compile-time after unroll
      bf16x8 (&nxt)[8] = (t & 1) ? b0 : b1;
      if(t < 8) ldB8(nxt, Bf, nq, t+1, DTOT, dblk, lane);
      __builtin_amdgcn_s_setprio(1);
      #pragma unroll
      for(int kk2=0; kk2<2; ++kk2){
        #pragma unroll
        for(int fm=0; fm<4; ++fm){
          int ra = wm*64 + fm*16 + lane16 + t;
          bf16x8 af = *(const bf16x8*)((const char*)Ah +
              ra*128 + (((kk2*32 + laneh*8)*2) ^ ((ra&7)<<4)));
          #pragma unroll
          for(int fn=0; fn<4; ++fn)
            acc[fm][fn] = __builtin_amdgcn_mfma_f32_16x16x32_bf16(af, cur[fn*2+kk2], acc[fm][fn], 0, 0, 0);
        }
      }
      __builtin_amdgcn_s_setprio(0);
    }
  }
  // ---- epilogue ----
  float* out_p = (EPI==3 && blockIdx.z==2) ? out_f2
               : out_f + (size_t)blockIdx.z * 16384 * 384;
  #pragma unroll
  for(int fm=0;fm<4;++fm){
    #pragma unroll
    for(int fn=0;fn<4;++fn){
      #pragma unroll
      for(int r=0;r<4;++r){
        int gr = m0 + wm*64 + fm*16 + laneh*4 + r;
        int gc = n0 + wn*64 + fn*16 + lane16;
        float c = acc[fm][fn][r];
        if(EPI==2){
          c += bias[gc];
          out_h[(size_t)gr*NOUT + gc] = f2bf(fmaxf(c, 0.f));
        } else {
          out_p[(size_t)gr*384 + gc] = c;
        }
      }
    }
  }
}

// bias-only add (conv2 fallback): out[i] = p[i] + bias[i % 384]
__global__ __launch_bounds__(256)
void k_bias(const float* __restrict__ p, const float* __restrict__ bias,
            float* __restrict__ out, int n4){
  for(int i = blockIdx.x*256 + threadIdx.x; i < n4; i += gridDim.x*256){
    f32x4 a = ((const f32x4*)p)[i];
    f32x4 bi = ((const f32x4*)bias)[i % 96];
    ((f32x4*)out)[i] = a + bi;
  }
}

// ---------------- attention: flash, cooperative LDS-staged K/V (R7, proven) ----------------

__global__ __launch_bounds__(256)
void k_attn(const unsigned short* __restrict__ Q,
            const unsigned short* __restrict__ Kb,
            const unsigned short* __restrict__ Vt,
            const void* __restrict__ mask,
            const unsigned* __restrict__ flag,
            unsigned short* __restrict__ O)
{
  __shared__ __attribute__((aligned(16))) unsigned short Ks[64*192];   // 24 KB
  __shared__ __attribute__((aligned(16))) unsigned short Vs[192*64];   // 24 KB
  __shared__ __attribute__((aligned(16))) unsigned short P_lds[4*16*64]; // 8 KB

  const int flat = blockIdx.y*gridDim.x + blockIdx.x;   // grid (16,32)
  const int w = (flat & 7)*64 + (flat >> 3);
  const int bh = w >> 4, qb = w & 15;
  const int b = bh >> 1, h = bh & 1;
  const int tid = threadIdx.x;
  const int wave = tid >> 6, lane = tid & 63;
  const int lane16 = lane & 15, laneh = lane >> 4;
  const int q0 = qb*64 + wave*16;
  const bool mbyte = (*flag != 0);
  const unsigned char* m8 = (const unsigned char*)mask;
  const int* m32 = (const int*)mask;
  unsigned short* Pw = P_lds + wave*1024;

  bf16x8 qa[6];
  {
    const unsigned short* Qrow = Q + ((size_t)bh*1024 + q0 + lane16)*192 + laneh*8;
    #pragma unroll
    for(int kk=0; kk<6; ++kk) qa[kk] = *(const bf16x8*)(Qrow + kk*32);
  }

  f32x4 accO[12];
  #pragma unroll
  for(int i=0;i<12;++i) accO[i] = (f32x4){0.f,0.f,0.f,0.f};
  float mrow[4], lrow[4];
  #pragma unroll
  for(int r=0;r<4;++r){ mrow[r] = -1e30f; lrow[r] = 0.f; }

  const float rs = 0.05103103630798288f;  // 1/sqrt(384)
  const size_t mbase = (size_t)b * 1024 * 1024;
  const unsigned short* Kbh = Kb + (size_t)bh*1024*192;
  const unsigned short* Vbh = Vt + (size_t)bh*192*1024;

  for(int t0=0; t0<1024; t0+=64){
    unsigned mskv[4][4];
    #pragma unroll
    for(int tf=0; tf<4; ++tf){
      #pragma unroll
      for(int r=0;r<4;++r){
        size_t mi = mbase + (size_t)(q0 + laneh*4 + r)*1024 + t0 + tf*16 + lane16;
        mskv[tf][r] = mbyte ? (unsigned)m8[mi] : (unsigned)m32[mi];
      }
    }
    __syncthreads();
    #pragma unroll
    for(int q=0;q<6;++q){
      int P = (q*256 + tid)*16;
      int row = P/384, cb = P%384;
      gload_lds16(Kbh + (size_t)(t0 + row)*192 + ((cb ^ ((row&7)<<4)) >> 1),
                  (char*)Ks + q*4096 + wave*1024);
    }
    #pragma unroll
    for(int q=0;q<6;++q){
      int P = (q*256 + tid)*16;
      int row = P >> 7, cb = P & 127;
      gload_lds16(Vbh + (size_t)row*1024 + t0 + ((cb ^ ((row&7)<<4)) >> 1),
                  (char*)Vs + q*4096 + wave*1024);
    }
    __syncthreads();
    f32x4 sc[4];
    #pragma unroll
    for(int i=0;i<4;++i) sc[i] = (f32x4){0.f,0.f,0.f,0.f};
    #pragma unroll
    for(int kk=0; kk<6; ++kk){
      #pragma unroll
      for(int tf=0; tf<4; ++tf){
        int tt = tf*16 + lane16;
        const bf16x8* kp = (const bf16x8*)((const char*)Ks +
            tt*384 + ((kk*64 + laneh*16) ^ ((tt&7)<<4)));
        sc[tf] = __builtin_amdgcn_mfma_f32_16x16x32_bf16(qa[kk], *kp, sc[tf], 0, 0, 0);
      }
    }
    #pragma unroll
    for(int tf=0; tf<4; ++tf)
      #pragma unroll
      for(int r=0;r<4;++r)
        sc[tf][r] = mskv[tf][r] ? -1e9f : sc[tf][r]*rs;
    float tm[4];
    #pragma unroll
    for(int r=0;r<4;++r){
      float v = fmaxf(fmaxf(sc[0][r],sc[1][r]), fmaxf(sc[2][r],sc[3][r]));
      v = fmaxf(v, __shfl_xor(v,1)); v = fmaxf(v, __shfl_xor(v,2));
      v = fmaxf(v, __shfl_xor(v,4)); v = fmaxf(v, __shfl_xor(v,8));
      tm[r] = v;
    }
    float scale_o[4];
    #pragma unroll
    for(int r=0;r<4;++r){
      float mn = fmaxf(mrow[r], tm[r]);
      scale_o[r] = __expf(mrow[r] - mn);
      mrow[r] = mn;
    }
    float ts[4] = {0.f,0.f,0.f,0.f};
    #pragma unroll
    for(int tf=0; tf<4; ++tf){
      #pragma unroll
      for(int r=0;r<4;++r){
        float p = __expf(sc[tf][r] - mrow[r]);
        ts[r] += p;
        Pw[(laneh*4 + r)*64 + tf*16 + lane16] = f2bf(p);
      }
    }
    #pragma unroll
    for(int r=0;r<4;++r){
      float v = ts[r];
      v += __shfl_xor(v,1); v += __shfl_xor(v,2); v += __shfl_xor(v,4); v += __shfl_xor(v,8);
      lrow[r] = lrow[r]*scale_o[r] + v;
    }
    #pragma unroll
    for(int ef=0; ef<12; ++ef)
      #pragma unroll
      for(int r=0;r<4;++r) accO[ef][r] *= scale_o[r];
    #pragma unroll
    for(int kk=0; kk<64; kk+=32){
      bf16x8 pa = *(const bf16x8*)&Pw[lane16*64 + kk + laneh*8];
      #pragma unroll
      for(int ef=0; ef<12; ++ef){
        int er = ef*16 + lane16;
        const bf16x8* vp = (const bf16x8*)((const char*)Vs +
            er*128 + (((kk + laneh*8)*2) ^ ((er&7)<<4)));
        accO[ef] = __builtin_amdgcn_mfma_f32_16x16x32_bf16(pa, *vp, accO[ef], 0, 0, 0);
      }
    }
  }
  #pragma unroll
  for(int ef=0; ef<12; ++ef){
    #pragma unroll
    for(int r=0;r<4;++r){
      int qr = q0 + laneh*4 + r;
      int e  = ef*16 + lane16;
      float o = accO[ef][r] / lrow[r];
      O[((size_t)b*1024 + qr)*384 + h*192 + e] = f2bf(o);
    }
  }
}

// ---------------- LayerNorm (1 wave per row of 384) ----------------

__global__ __launch_bounds__(256)
void k_ln(const float* __restrict__ a, const float* __restrict__ resid,
          const float* __restrict__ g, const float* __restrict__ beta,
          float* __restrict__ outf, unsigned short* __restrict__ outbf)
{
  const int row = blockIdx.x*4 + (threadIdx.x >> 6);
  const int lane = threadIdx.x & 63;
  const float* pa = a + (size_t)row*384;
  const float* pr = resid + (size_t)row*384;
  float v[6], s = 0.f, s2 = 0.f;
  #pragma unroll
  for(int j=0;j<6;++j){
    int e = lane + j*64;
    float t = pa[e] + pr[e];
    v[j] = t; s += t; s2 += t*t;
  }
  #pragma unroll
  for(int o=1;o<64;o<<=1){ s += __shfl_xor(s,o); s2 += __shfl_xor(s2,o); }
  float mean = s * (1.f/384.f);
  float var  = s2 * (1.f/384.f) - mean*mean;
  float inv  = rsqrtf(var + 1e-5f);
  #pragma unroll
  for(int j=0;j<6;++j){
    int e = lane + j*64;
    float t = (v[j]-mean)*inv*g[e] + beta[e];
    if(outf)  outf[(size_t)row*384 + e] = t;
    if(outbf) outbf[(size_t)row*384 + e] = f2bf(t);
  }
}

// fused: LN( p0+p1+p2+bias  + resid ) -> outf   (conv2 3-slab reduce + LN2)
__global__ __launch_bounds__(256)
void k_lnred3(const float* __restrict__ p0, const float* __restrict__ p2,
              const float* __restrict__ bias, const float* __restrict__ resid,
              const float* __restrict__ g, const float* __restrict__ beta,
              float* __restrict__ outf)
{
  const int row = blockIdx.x*4 + (threadIdx.x >> 6);
  const int lane = threadIdx.x & 63;
  const float* p1 = p0 + (size_t)16384*384;
  const size_t base = (size_t)row*384;
  float v[6], s = 0.f, s2 = 0.f;
  #pragma unroll
  for(int j=0;j<6;++j){
    int e = lane + j*64;
    float t = p0[base+e] + p1[base+e] + p2[base+e] + bias[e] + resid[base+e];
    v[j] = t; s += t; s2 += t*t;
  }
  #pragma unroll
  for(int o=1;o<64;o<<=1){ s += __shfl_xor(s,o); s2 += __shfl_xor(s2,o); }
  float mean = s * (1.f/384.f);
  float var  = s2 * (1.f/384.f) - mean*mean;
  float inv  = rsqrtf(var + 1e-5f);
  #pragma unroll
  for(int j=0;j<6;++j){
    int e = lane + j*64;
    outf[base + e] = (v[j]-mean)*inv*g[e] + beta[e];
  }
}

// ---------------- host ----------------

extern "C" void kernel_launch(void* const* d_in, const int* in_sizes, int n_in,
                              void* d_out, int out_size, void* d_ws, size_t ws_size,
                              hipStream_t stream)
{
  const float* x   = (const float*)d_in[0];
  const void*  mask= d_in[1];
  const float* Wq  = (const float*)d_in[2];
  const float* bq  = (const float*)d_in[3];
  const float* Wk  = (const float*)d_in[4];
  const float* bk  = (const float*)d_in[5];
  const float* Wv  = (const float*)d_in[6];
  const float* bv  = (const float*)d_in[7];
  const float* Wo  = (const float*)d_in[8];
  const float* bo  = (const float*)d_in[9];
  const float* Wc1 = (const float*)d_in[10];
  const float* bc1 = (const float*)d_in[11];
  const float* Wc2 = (const float*)d_in[12];
  const float* bc2 = (const float*)d_in[13];
  const float* g1  = (const float*)d_in[14];
  const float* be1 = (const float*)d_in[15];
  const float* g2  = (const float*)d_in[16];
  const float* be2 = (const float*)d_in[17];

  // R13-R15 (proven) layout; wc1t/wc2t hold frag-ordered weights (same 10.6 MB).
  char* ws = (char*)d_ws;
  size_t off = 0;
  auto alloc = [&](size_t bytes)->char*{
    char* p = ws + off; off += (bytes + 255) & ~(size_t)255; return p;
  };
  unsigned short* zp   = (unsigned short*)alloc(4096);
  unsigned*       flag = (unsigned*)alloc(256);
  unsigned short* wqkv = (unsigned short*)alloc((size_t)1152*384*2);
  float*          bqkv = (float*)alloc((size_t)1152*4);
  unsigned short* wot  = (unsigned short*)alloc((size_t)384*384*2);
  unsigned short* wc1t = (unsigned short*)alloc((size_t)1536*3456*2);   // 10368 KB frag buf
  unsigned short* wc2t = (unsigned short*)alloc((size_t)384*13824*2);   // 10368 KB frag buf
  unsigned short* xbf  = (unsigned short*)alloc((size_t)16384*384*2);   // 12582912 B
  unsigned short* Qb   = (unsigned short*)alloc((size_t)32*1024*192*2); // 12582912 B (contiguous w/ xbf)
  unsigned short* Kbuf = (unsigned short*)alloc((size_t)32*1024*192*2);
  unsigned short* Vt   = (unsigned short*)alloc((size_t)32*192*1024*2);
  float*          yb   = (float*)alloc((size_t)16384*384*4);
  unsigned short* hb   = (unsigned short*)alloc((size_t)16384*1536*2);
  // overlays (lifetimes strictly ordered on the stream):
  unsigned short* Obf  = xbf;          // attention out (xbf dead after QKV gemm; consumed by Wo gemm)
  unsigned short* x1bf = Qb;           // LN1 bf16 out (Qb dead after attn; consumed by conv1)
  float*          x1f  = (float*)Kbuf; // LN1 f32 out, spans Kbuf+Vt (dead after attn)
  float*          zb   = yb;           // conv2 out, fallback only (yb dead after LN1)
  // conv2 z=3 split: slabs 0,1 in dedicated pb tail (guarded); slab 2 overlays xbf+Qb
  // (exactly 25165824 B contiguous; both dead once conv1 has consumed x1bf). Proven R8-R15.
  const size_t pb_bytes = (size_t)2*16384*384*4;
  const bool   splitk   = (ws_size >= off + pb_bytes);
  float*       pb       = (float*)alloc(pb_bytes);
  float*       slab2    = (float*)xbf;

  k_misc<<<1,256,0,stream>>>((const unsigned char*)mask, flag, zp);
  k_cast4<<<2048,256,0,stream>>>(x, xbf, 16384*384/4);
  k_prep_qkv<<<1728,256,0,stream>>>(Wq,Wk,Wv,bq,bk,bv,wqkv,bqkv);
  k_tr<<<dim3(12,12),256,0,stream>>>(Wo, wot, 384, 384);
  k_prepB<384,1536><<<2592,256,0,stream>>>(Wc1, wc1t);   // 10368 frags x 64 lanes
  k_prepB<1536,384><<<2592,256,0,stream>>>(Wc2, wc2t);

  // QKV projection: [16384,384] x [384,1152]
  k_gemm<0><<<dim3(9,128),256,0,stream>>>(xbf, wqkv, bqkv, Qb, Kbuf, Vt,
                                          nullptr, 384, 384);
  // attention (cooperative LDS-staged K/V)
  k_attn<<<dim3(16,32),256,0,stream>>>(Qb, Kbuf, Vt, mask, flag, Obf);
  // O @ Wo + bo
  k_gemm<1><<<dim3(3,128),256,0,stream>>>(Obf, wot, bo, nullptr,nullptr,nullptr,
                                          yb, 384, 384);
  // LN1 (adds residual x)
  k_ln<<<4096,256,0,stream>>>(yb, x, g1, be1, x1f, x1bf);
  // conv1: B-frag-direct + prefetch + setprio, relu  (grid 12x128 = 1536 blocks)
  k_conv<2,384,1536><<<dim3(12,128,1),256,0,stream>>>(x1bf, wc1t, bc1, hb, nullptr, nullptr, zp);
  if(splitk){
    // conv2: z=3 over d (dper=8) -> slabs 0,1 in pb, slab 2 in xbf+Qb overlay
    k_conv<3,1536,384><<<dim3(3,128,3),256,0,stream>>>(hb, wc2t, nullptr, nullptr, pb, slab2, zp);
    // fused 3-slab reduce + bias + residual + LN2 -> d_out
    k_lnred3<<<4096,256,0,stream>>>(pb, slab2, bc2, x1f, g2, be2, (float*)d_out);
  } else {
    // fallback: single-z f32 partial into zb, bias add, then LN2
    k_conv<3,1536,384><<<dim3(3,128,1),256,0,stream>>>(hb, wc2t, nullptr, nullptr, zb, nullptr, zp);
    k_bias<<<2048,256,0,stream>>>(zb, bc2, zb, 16384*384/4);
    k_ln<<<4096,256,0,stream>>>(zb, x1f, g2, be2, (float*)d_out, nullptr);
  }
}